// Round 5
// baseline (1456.636 us; speedup 1.0000x reference)
//
#include <hip/hip_runtime.h>
#include <hip/hip_fp16.h>

#define D_DIM 1024
#define E_NUM 4
#define F_DIM 4096
#define NTOK 8192         // B*S = 4*2048
#define MT 64             // tokens per tile (fallback fused kernel)
#define FC 256
#define KC 256
#define FHALF 2048

typedef _Float16 half8_t __attribute__((ext_vector_type(8)));
typedef _Float16 half4_t __attribute__((ext_vector_type(4)));
typedef float floatx4 __attribute__((ext_vector_type(4)));

// ---------------- gating: top-2 expert selection + routing lists ----------------
__global__ __launch_bounds__(256) void gate_kernel(
    const float* __restrict__ x, const float* __restrict__ Wg,
    const float* __restrict__ bg, int* __restrict__ cnt, int* __restrict__ lists)
{
    int wave = threadIdx.x >> 6;
    int lane = threadIdx.x & 63;
    int tok = blockIdx.x * 4 + wave;
    if (tok >= NTOK) return;
    const float* xr = x + (size_t)tok * D_DIM;
    double a0 = 0.0, a1 = 0.0, a2 = 0.0, a3 = 0.0;
    #pragma unroll
    for (int it = 0; it < 4; ++it) {
        int i0 = it * 256 + lane * 4;
        float4 xv = *(const float4*)(xr + i0);
        float4 w0 = *(const float4*)(Wg + (size_t)i0 * 4);
        float4 w1 = *(const float4*)(Wg + (size_t)i0 * 4 + 4);
        float4 w2 = *(const float4*)(Wg + (size_t)i0 * 4 + 8);
        float4 w3 = *(const float4*)(Wg + (size_t)i0 * 4 + 12);
        a0 += (double)xv.x * w0.x + (double)xv.y * w1.x
            + (double)xv.z * w2.x + (double)xv.w * w3.x;
        a1 += (double)xv.x * w0.y + (double)xv.y * w1.y
            + (double)xv.z * w2.y + (double)xv.w * w3.y;
        a2 += (double)xv.x * w0.z + (double)xv.y * w1.z
            + (double)xv.z * w2.z + (double)xv.w * w3.z;
        a3 += (double)xv.x * w0.w + (double)xv.y * w1.w
            + (double)xv.z * w2.w + (double)xv.w * w3.w;
    }
    #pragma unroll
    for (int off = 32; off > 0; off >>= 1) {
        a0 += __shfl_down(a0, off);
        a1 += __shfl_down(a1, off);
        a2 += __shfl_down(a2, off);
        a3 += __shfl_down(a3, off);
    }
    if (lane == 0) {
        double lg[4] = { a0 + (double)bg[0], a1 + (double)bg[1],
                         a2 + (double)bg[2], a3 + (double)bg[3] };
        int i1 = 0;
        for (int e = 1; e < 4; ++e) if (lg[e] > lg[i1]) i1 = e;   // first max wins
        int i2 = -1;
        for (int e = 0; e < 4; ++e) {
            if (e == i1) continue;
            if (i2 < 0 || lg[e] > lg[i2]) i2 = e;
        }
        int p1 = atomicAdd(&cnt[i1], 1);
        lists[i1 * NTOK + p1] = tok;
        int p2 = atomicAdd(&cnt[i2], 1);
        lists[i2 * NTOK + p2] = tok;
    }
}

// ---------------- prep: x fp32 -> fp16 (fallback path only) ----------------
__global__ __launch_bounds__(256) void cvt_x_kernel(
    const float* __restrict__ x, _Float16* __restrict__ xh)
{
    size_t i = ((size_t)blockIdx.x * 256 + threadIdx.x) * 8;
    float4 v0 = *(const float4*)(x + i);
    float4 v1 = *(const float4*)(x + i + 4);
    half8_t h = { (_Float16)v0.x, (_Float16)v0.y, (_Float16)v0.z, (_Float16)v0.w,
                  (_Float16)v1.x, (_Float16)v1.y, (_Float16)v1.z, (_Float16)v1.w };
    *(half8_t*)(xh + i) = h;
}

// ---------------- prep: transpose fp32 [z][R][C] -> fp16 [z][C][R] ----------------
__global__ __launch_bounds__(256) void transpose_fp16_kernel(
    const float* __restrict__ src, _Float16* __restrict__ dst, int R, int C)
{
    __shared__ _Float16 t[32][33];
    int c0 = blockIdx.x * 32, r0 = blockIdx.y * 32;
    const float* s = src + (size_t)blockIdx.z * R * C;
    _Float16* d = dst + (size_t)blockIdx.z * R * C;
    #pragma unroll
    for (int i = 0; i < 4; ++i) {
        int r = threadIdx.y + i * 8;
        t[r][threadIdx.x] = (_Float16)s[(size_t)(r0 + r) * C + c0 + threadIdx.x];
    }
    __syncthreads();
    #pragma unroll
    for (int i = 0; i < 4; ++i) {
        int rr = threadIdx.y + i * 8;
        d[(size_t)(c0 + rr) * R + r0 + threadIdx.x] = t[threadIdx.x][rr];
    }
}

// ---------------- prep: pack fp32 [z][R(k)][C(n)] into MFMA fragment tiles ----------
__global__ __launch_bounds__(256) void tile_pack_kernel(
    const float* __restrict__ src, _Float16* __restrict__ dst, int R, int C)
{
    __shared__ _Float16 t2[32][36];
    int r0 = blockIdx.y * 32, c0 = blockIdx.x * 32;
    const float* s = src + (size_t)blockIdx.z * R * C;
    _Float16* d = dst + (size_t)blockIdx.z * R * C;
    int tx = threadIdx.x & 31, ty = threadIdx.x >> 5;
    #pragma unroll
    for (int i = 0; i < 4; ++i) {
        int r = ty + i * 8;
        t2[tx][r] = (_Float16)s[(size_t)(r0 + r) * C + c0 + tx];
    }
    __syncthreads();
    int KB = R >> 5;
    int idx = threadIdx.x * 4;
    int frag_h = idx >> 9;
    int rem = idx & 511;
    int quad = rem >> 7, ln = (rem >> 3) & 15, j0 = rem & 7;
    int cl = frag_h * 16 + ln, rl = quad * 8 + j0;
    half4_t v = { t2[cl][rl], t2[cl][rl + 1], t2[cl][rl + 2], t2[cl][rl + 3] };
    size_t off = ((size_t)(((c0 >> 4) + frag_h) * KB + (r0 >> 5))) * 512 + rem;
    *(half4_t*)&d[off] = v;
}

// ---------------- work-item decode: block -> (expert, tile, count, row base) -------
__device__ __forceinline__ int decode_tile(const int* cnt, int bi, int mtile,
                                           int& expert, int& tile, int& mcnt,
                                           int& rowbase)
{
    int rem = bi; rowbase = 0;
    for (int e = 0; e < E_NUM; ++e) {
        int n = cnt[e];
        int nb = (n + mtile - 1) / mtile;
        if (rem < nb) {
            expert = e; tile = rem; mcnt = min(mtile, n - rem * mtile);
            return 1;
        }
        rem -= nb; rowbase += n;
    }
    return 0;
}

// ---------------- pass 1: H = swish(Xgather · W1 + b1), fp16 out -------------------
// 256 threads, 4 waves, 128x128 tile, BK=64. B = W1t [E][F][D] (n-major fp16).
__global__ __launch_bounds__(256, 3) void gemm1_kernel(
    const float* __restrict__ x, const _Float16* __restrict__ W1t,
    const float* __restrict__ b1, const int* __restrict__ cnt,
    const int* __restrict__ lists, _Float16* __restrict__ H)
{
    __shared__ _Float16 As[128][72];
    __shared__ _Float16 Bs[128][72];
    __shared__ int tks[128];

    int expert, tile, mcnt, rowbase;
    if (!decode_tile(cnt, blockIdx.x, 128, expert, tile, mcnt, rowbase)) return;
    int n0 = blockIdx.y * 128;

    if (threadIdx.x < 128) {
        int idx = tile * 128 + (int)threadIdx.x;
        tks[threadIdx.x] = lists[expert * NTOK + ((int)threadIdx.x < mcnt ? idx : tile * 128)];
    }
    __syncthreads();

    const _Float16* Bt = W1t + (size_t)expert * D_DIM * F_DIM + (size_t)n0 * D_DIM;
    int w = threadIdx.x >> 6, lane = threadIdx.x & 63;
    int quad = lane >> 4, ln = lane & 15;
    int mh = (w & 1) * 64, nh = (w >> 1) * 64;

    floatx4 acc[4][4];
    #pragma unroll
    for (int mt = 0; mt < 4; ++mt)
        #pragma unroll
        for (int nt = 0; nt < 4; ++nt)
            acc[mt][nt] = (floatx4){0.f, 0.f, 0.f, 0.f};

    int srow = threadIdx.x >> 1;          // 0..127
    int scol = (threadIdx.x & 1) * 32;    // 0 or 32 (halves)
    const float* Ag = x + (size_t)tks[srow] * D_DIM + scol;
    const _Float16* Bg = Bt + (size_t)srow * D_DIM + scol;

    for (int k0 = 0; k0 < D_DIM; k0 += 64) {
        // stage A (fp32 -> fp16) and B (fp16)
        {
            const float4* xr = (const float4*)(Ag + k0);
            #pragma unroll
            for (int j = 0; j < 4; ++j) {
                float4 v0 = xr[2 * j], v1 = xr[2 * j + 1];
                half8_t h = { (_Float16)v0.x, (_Float16)v0.y, (_Float16)v0.z, (_Float16)v0.w,
                              (_Float16)v1.x, (_Float16)v1.y, (_Float16)v1.z, (_Float16)v1.w };
                *(half8_t*)&As[srow][scol + j * 8] = h;
            }
            const half8_t* br = (const half8_t*)(Bg + k0);
            #pragma unroll
            for (int j = 0; j < 4; ++j)
                *(half8_t*)&Bs[srow][scol + j * 8] = br[j];
        }
        __syncthreads();
        #pragma unroll
        for (int ks = 0; ks < 2; ++ks) {
            int kk = ks * 32 + quad * 8;
            half8_t a[4], b[4];
            #pragma unroll
            for (int mt = 0; mt < 4; ++mt)
                a[mt] = *(const half8_t*)&As[mh + mt * 16 + ln][kk];
            #pragma unroll
            for (int nt = 0; nt < 4; ++nt)
                b[nt] = *(const half8_t*)&Bs[nh + nt * 16 + ln][kk];
            #pragma unroll
            for (int nt = 0; nt < 4; ++nt)
                #pragma unroll
                for (int mt = 0; mt < 4; ++mt)
                    acc[mt][nt] = __builtin_amdgcn_mfma_f32_16x16x32_f16(
                        a[mt], b[nt], acc[mt][nt], 0, 0, 0);
        }
        __syncthreads();
    }

    // epilogue: bias + swish -> H fp16
    size_t hbase = (size_t)(rowbase + tile * 128);
    #pragma unroll
    for (int nt = 0; nt < 4; ++nt) {
        int col = n0 + nh + nt * 16 + ln;
        float b1v = b1[expert * F_DIM + col];
        #pragma unroll
        for (int mt = 0; mt < 4; ++mt)
            #pragma unroll
            for (int r = 0; r < 4; ++r) {
                int row = mh + mt * 16 + quad * 4 + r;
                if (row < mcnt) {
                    float v = acc[mt][nt][r] + b1v;
                    H[(hbase + row) * F_DIM + col] = (_Float16)(v / (1.f + __expf(-v)));
                }
            }
    }
}

// ---------------- pass 2: out[tok] += H · W2 + b2 (atomic scatter) -----------------
// B = W2t [E][D][F] (n-major fp16). K = F = 4096.
__global__ __launch_bounds__(256, 3) void gemm2_kernel(
    const _Float16* __restrict__ H, const _Float16* __restrict__ W2t,
    const float* __restrict__ b2, const int* __restrict__ cnt,
    const int* __restrict__ lists, float* __restrict__ out)
{
    __shared__ _Float16 As[128][72];
    __shared__ _Float16 Bs[128][72];
    __shared__ int tks[128];

    int expert, tile, mcnt, rowbase;
    if (!decode_tile(cnt, blockIdx.x, 128, expert, tile, mcnt, rowbase)) return;
    int n0 = blockIdx.y * 128;

    if (threadIdx.x < 128) {
        int idx = tile * 128 + (int)threadIdx.x;
        tks[threadIdx.x] = lists[expert * NTOK + ((int)threadIdx.x < mcnt ? idx : tile * 128)];
    }
    __syncthreads();

    const _Float16* Bt = W2t + (size_t)expert * D_DIM * F_DIM + (size_t)n0 * F_DIM;
    int w = threadIdx.x >> 6, lane = threadIdx.x & 63;
    int quad = lane >> 4, ln = lane & 15;
    int mh = (w & 1) * 64, nh = (w >> 1) * 64;

    floatx4 acc[4][4];
    #pragma unroll
    for (int mt = 0; mt < 4; ++mt)
        #pragma unroll
        for (int nt = 0; nt < 4; ++nt)
            acc[mt][nt] = (floatx4){0.f, 0.f, 0.f, 0.f};

    int srow = threadIdx.x >> 1;
    int scol = (threadIdx.x & 1) * 32;
    int arow_l = srow < mcnt ? srow : 0;          // clamp: never read beyond expert seg
    const _Float16* Ag = H + (size_t)(rowbase + tile * 128 + arow_l) * F_DIM + scol;
    const _Float16* Bg = Bt + (size_t)srow * F_DIM + scol;

    for (int k0 = 0; k0 < F_DIM; k0 += 64) {
        {
            const half8_t* ar = (const half8_t*)(Ag + k0);
            #pragma unroll
            for (int j = 0; j < 4; ++j)
                *(half8_t*)&As[srow][scol + j * 8] = ar[j];
            const half8_t* br = (const half8_t*)(Bg + k0);
            #pragma unroll
            for (int j = 0; j < 4; ++j)
                *(half8_t*)&Bs[srow][scol + j * 8] = br[j];
        }
        __syncthreads();
        #pragma unroll
        for (int ks = 0; ks < 2; ++ks) {
            int kk = ks * 32 + quad * 8;
            half8_t a[4], b[4];
            #pragma unroll
            for (int mt = 0; mt < 4; ++mt)
                a[mt] = *(const half8_t*)&As[mh + mt * 16 + ln][kk];
            #pragma unroll
            for (int nt = 0; nt < 4; ++nt)
                b[nt] = *(const half8_t*)&Bs[nh + nt * 16 + ln][kk];
            #pragma unroll
            for (int nt = 0; nt < 4; ++nt)
                #pragma unroll
                for (int mt = 0; mt < 4; ++mt)
                    acc[mt][nt] = __builtin_amdgcn_mfma_f32_16x16x32_f16(
                        a[mt], b[nt], acc[mt][nt], 0, 0, 0);
        }
        __syncthreads();
    }

    // epilogue: scatter-add to out (b2 added once per (pair, col) here)
    #pragma unroll
    for (int nt = 0; nt < 4; ++nt) {
        int col = n0 + nh + nt * 16 + ln;
        float b2v = b2[expert * D_DIM + col];
        #pragma unroll
        for (int mt = 0; mt < 4; ++mt)
            #pragma unroll
            for (int r = 0; r < 4; ++r) {
                int row = mh + mt * 16 + quad * 4 + r;
                if (row < mcnt)
                    atomicAdd(&out[(size_t)tks[row] * D_DIM + col],
                              acc[mt][nt][r] + b2v);
            }
    }
}

// ---------------- fallback: round-4 fused kernel (ws too small for 2-pass) ---------
__global__ __launch_bounds__(512, 2) void moe_fast_kernel(
    const _Float16* __restrict__ xh, const _Float16* __restrict__ W1m,
    const float* __restrict__ b1, const _Float16* __restrict__ W2m,
    const float* __restrict__ b2, const int* __restrict__ cnt,
    const int* __restrict__ lists, float* __restrict__ out)
{
    __shared__ _Float16 Xs[MT][KC + 8];
    __shared__ _Float16 Hs[MT][FC + 8];
    __shared__ int tks[MT];

    int fhalf = blockIdx.x & 1;
    int bi = blockIdx.x >> 1;
    int expert, tile, mcnt, rowbase;
    if (!decode_tile(cnt, bi, MT, expert, tile, mcnt, rowbase)) return;

    if (threadIdx.x < MT) {
        int idx = tile * MT + (int)threadIdx.x;
        tks[threadIdx.x] = lists[expert * NTOK + ((int)threadIdx.x < mcnt ? idx : tile * MT)];
    }
    __syncthreads();

    const half8_t* W1f = (const half8_t*)(W1m + (size_t)expert * D_DIM * F_DIM);
    const half8_t* W2f = (const half8_t*)(W2m + (size_t)expert * D_DIM * F_DIM);
    const float* b1e = b1 + (size_t)expert * F_DIM;
    const float* b2e = b2 + (size_t)expert * D_DIM;

    int w = threadIdx.x >> 6;
    int lane = threadIdx.x & 63;
    int quad = lane >> 4;
    int ln = lane & 15;

    floatx4 oacc[4][8];
    #pragma unroll
    for (int mt = 0; mt < 4; ++mt)
        #pragma unroll
        for (int nt = 0; nt < 8; ++nt)
            oacc[mt][nt] = (floatx4){0.f, 0.f, 0.f, 0.f};

    int fbase = fhalf * FHALF;
    int srow = threadIdx.x >> 3;
    int stg  = threadIdx.x & 7;

    for (int fc = 0; fc < FHALF / FC; ++fc) {
        int f0 = fbase + fc * FC;
        int fb0 = (f0 >> 4) + w * 2;

        floatx4 hacc[4][2];
        #pragma unroll
        for (int mt = 0; mt < 4; ++mt) { hacc[mt][0] = (floatx4){0.f,0.f,0.f,0.f};
                                         hacc[mt][1] = (floatx4){0.f,0.f,0.f,0.f}; }

        for (int kc = 0; kc < D_DIM / KC; ++kc) {
            int k0 = kc * KC;
            {
                const _Float16* xr = xh + (size_t)tks[srow] * D_DIM + k0 + stg * 32;
                half8_t v0 = *(const half8_t*)(xr);
                half8_t v1 = *(const half8_t*)(xr + 8);
                half8_t v2 = *(const half8_t*)(xr + 16);
                half8_t v3 = *(const half8_t*)(xr + 24);
                *(half8_t*)&Xs[srow][stg * 32]      = v0;
                *(half8_t*)&Xs[srow][stg * 32 + 8]  = v1;
                *(half8_t*)&Xs[srow][stg * 32 + 16] = v2;
                *(half8_t*)&Xs[srow][stg * 32 + 24] = v3;
            }
            __syncthreads();
            #pragma unroll
            for (int ks = 0; ks < KC / 32; ++ks) {
                int kk = ks * 32 + quad * 8;
                int kb = kc * 8 + ks;
                half8_t a[4];
                #pragma unroll
                for (int mt = 0; mt < 4; ++mt)
                    a[mt] = *(const half8_t*)&Xs[mt * 16 + ln][kk];
                #pragma unroll
                for (int nt = 0; nt < 2; ++nt) {
                    half8_t b = W1f[((size_t)((fb0 + nt) * 32 + kb)) * 64 + lane];
                    #pragma unroll
                    for (int mt = 0; mt < 4; ++mt)
                        hacc[mt][nt] = __builtin_amdgcn_mfma_f32_16x16x32_f16(
                            a[mt], b, hacc[mt][nt], 0, 0, 0);
                }
            }
            __syncthreads();
        }

        #pragma unroll
        for (int nt = 0; nt < 2; ++nt) {
            int fcol_l = w * 32 + nt * 16 + ln;
            float b1v = b1e[f0 + fcol_l];
            #pragma unroll
            for (int mt = 0; mt < 4; ++mt)
                #pragma unroll
                for (int r = 0; r < 4; ++r) {
                    float v = hacc[mt][nt][r] + b1v;
                    float hs = v / (1.f + __expf(-v));
                    Hs[mt * 16 + quad * 4 + r][fcol_l] = (_Float16)hs;
                }
        }
        __syncthreads();

        #pragma unroll
        for (int ks = 0; ks < FC / 32; ++ks) {
            int kk = ks * 32 + quad * 8;
            int fkb = (f0 >> 5) + ks;
            half8_t a[4];
            #pragma unroll
            for (int mt = 0; mt < 4; ++mt)
                a[mt] = *(const half8_t*)&Hs[mt * 16 + ln][kk];
            #pragma unroll
            for (int nt = 0; nt < 8; ++nt) {
                int db = w * 8 + nt;
                half8_t b = W2f[((size_t)(db * 128 + fkb)) * 64 + lane];
                #pragma unroll
                for (int mt = 0; mt < 4; ++mt)
                    oacc[mt][nt] = __builtin_amdgcn_mfma_f32_16x16x32_f16(
                        a[mt], b, oacc[mt][nt], 0, 0, 0);
            }
        }
        __syncthreads();
    }

    #pragma unroll
    for (int mt = 0; mt < 4; ++mt) {
        #pragma unroll
        for (int r = 0; r < 4; ++r) {
            int row = mt * 16 + quad * 4 + r;
            if (row >= mcnt) continue;
            float* orow = out + (size_t)tks[row] * D_DIM;
            #pragma unroll
            for (int nt = 0; nt < 8; ++nt) {
                int dcol = w * 128 + nt * 16 + ln;
                float v = oacc[mt][nt][r];
                if (fhalf == 0) v += b2e[dcol];
                atomicAdd(orow + dcol, v);
            }
        }
    }
}

extern "C" void kernel_launch(void* const* d_in, const int* in_sizes, int n_in,
                              void* d_out, int out_size, void* d_ws, size_t ws_size,
                              hipStream_t stream) {
    const float* x  = (const float*)d_in[0];
    const float* Wg = (const float*)d_in[1];
    const float* bg = (const float*)d_in[2];
    const float* W1 = (const float*)d_in[3];
    const float* b1 = (const float*)d_in[4];
    const float* W2 = (const float*)d_in[5];
    const float* b2 = (const float*)d_in[6];
    float* out = (float*)d_out;

    // shared prefix: [cnt 16B][pad][lists @512B, 128KB]
    const size_t OFF_LISTS = 512;
    const size_t OFF_WA    = OFF_LISTS + (size_t)E_NUM * NTOK * 4;      // 131584
    const size_t SZ_W      = (size_t)E_NUM * D_DIM * F_DIM * 2;         // 32 MB
    // two-pass layout: [W1t][W2t][H 128MB]
    const size_t OFF_W2T   = OFF_WA + SZ_W;
    const size_t OFF_H     = OFF_W2T + SZ_W;
    const size_t SZ_H      = (size_t)(2 * NTOK) * F_DIM * 2;            // 128 MB
    const size_t WS_2P     = OFF_H + SZ_H;                              // ~192.1 MB
    // fallback layout: [W1m][W2m][xh 16MB]
    const size_t OFF_XH    = OFF_W2T + SZ_W;
    const size_t WS_FAST   = OFF_XH + (size_t)NTOK * D_DIM * 2;

    int* cnt   = (int*)d_ws;
    int* lists = (int*)((char*)d_ws + OFF_LISTS);

    hipMemsetAsync(cnt, 0, 16, stream);
    hipMemsetAsync(d_out, 0, (size_t)out_size * sizeof(float), stream);

    gate_kernel<<<NTOK / 4, 256, 0, stream>>>(x, Wg, bg, cnt, lists);

    if (ws_size >= WS_2P) {
        _Float16* W1t = (_Float16*)((char*)d_ws + OFF_WA);
        _Float16* W2t = (_Float16*)((char*)d_ws + OFF_W2T);
        _Float16* H   = (_Float16*)((char*)d_ws + OFF_H);

        // W1 [E][D][F] -> W1t [E][F][D];  W2 [E][F][D] -> W2t [E][D][F]
        transpose_fp16_kernel<<<dim3(F_DIM / 32, D_DIM / 32, E_NUM), dim3(32, 8), 0, stream>>>(
            W1, W1t, D_DIM, F_DIM);
        transpose_fp16_kernel<<<dim3(D_DIM / 32, F_DIM / 32, E_NUM), dim3(32, 8), 0, stream>>>(
            W2, W2t, F_DIM, D_DIM);

        // worst-case m-items: sum_e ceil(cnt[e]/128) <= 131
        gemm1_kernel<<<dim3(131, F_DIM / 128), 256, 0, stream>>>(
            x, W1t, b1, cnt, lists, H);
        gemm2_kernel<<<dim3(131, D_DIM / 128), 256, 0, stream>>>(
            H, W2t, b2, cnt, lists, out);
    } else {
        _Float16* W1m = (_Float16*)((char*)d_ws + OFF_WA);
        _Float16* W2m = (_Float16*)((char*)d_ws + OFF_W2T);
        _Float16* xh  = (_Float16*)((char*)d_ws + OFF_XH);

        cvt_x_kernel<<<(NTOK * D_DIM) / (256 * 8), 256, 0, stream>>>(x, xh);
        tile_pack_kernel<<<dim3(F_DIM / 32, D_DIM / 32, E_NUM), 256, 0, stream>>>(
            W1, W1m, D_DIM, F_DIM);
        tile_pack_kernel<<<dim3(D_DIM / 32, F_DIM / 32, E_NUM), 256, 0, stream>>>(
            W2, W2m, F_DIM, D_DIM);

        moe_fast_kernel<<<520, 512, 0, stream>>>(xh, W1m, b1, W2m, b2, cnt, lists, out);
    }
}